// Round 1
// baseline (7991.296 us; speedup 1.0000x reference)
//
#include <hip/hip_runtime.h>
#include <math.h>

// Shapes (fixed): B=2, S=1024, D=2048, H=16, DH=128, F=8192
#define SEQL 1024
#define NBATCH 2
#define NHEAD 16
#define DHEAD 128
#define DM 2048
#define FF 8192
#define TOK 2048   // B*S

// KEY IDENTITY: attn_pass(rotate_half(Q), rotate_half(K), V) == attn_pass(Q,K,V):
//   rot(q)·rot(k) = q·k  and  rot(q)^2·rot(k)^2 = q^2·k^2 (reordered sum).
// Hence o1 == o2 and g*o1+(1-g)*o2 == o1 -> gate_w unused, one attention pass.

// ---------------------------------------------------------------- RMSNorm
__global__ __launch_bounds__(256)
void rmsnorm_k(const float* __restrict__ x, const float* __restrict__ g,
               float* __restrict__ o) {
  const int row = blockIdx.x;
  const int t = threadIdx.x;
  const float4* xr = (const float4*)(x + (size_t)row * DM);
  float4 v0 = xr[t], v1 = xr[t + 256];
  float ss = v0.x*v0.x + v0.y*v0.y + v0.z*v0.z + v0.w*v0.w
           + v1.x*v1.x + v1.y*v1.y + v1.z*v1.z + v1.w*v1.w;
#pragma unroll
  for (int m = 1; m < 64; m <<= 1) ss += __shfl_xor(ss, m, 64);
  __shared__ float wsum[4];
  if ((t & 63) == 0) wsum[t >> 6] = ss;
  __syncthreads();
  float tot = wsum[0] + wsum[1] + wsum[2] + wsum[3];
  float sc = rsqrtf(tot * (1.0f / DM) + 1e-6f);
  const float4* gr = (const float4*)g;
  float4 g0 = gr[t], g1 = gr[t + 256];
  float4 o0, o1;
  o0.x = v0.x * sc * g0.x; o0.y = v0.y * sc * g0.y;
  o0.z = v0.z * sc * g0.z; o0.w = v0.w * sc * g0.w;
  o1.x = v1.x * sc * g1.x; o1.y = v1.y * sc * g1.y;
  o1.z = v1.z * sc * g1.z; o1.w = v1.w * sc * g1.w;
  float4* orow = (float4*)(o + (size_t)row * DM);
  orow[t] = o0; orow[t + 256] = o1;
}

// ------------------------------------------------- NT GEMM: C = A * B^T (+res)
// A: MxK row-major, B: NxK row-major. 128x128 tile, BK=16, 256 thr, 8x8 micro.
// blockIdx.z selects among up to 3 (B,C) pairs sharing the same A.
__global__ __launch_bounds__(256)
void gemm_nt(const float* __restrict__ A, const float* __restrict__ B0,
             const float* __restrict__ B1, const float* __restrict__ B2,
             float* __restrict__ C0, float* __restrict__ C1, float* __restrict__ C2,
             const float* __restrict__ res, int M, int N, int K) {
  const float* Bw = (blockIdx.z == 0) ? B0 : (blockIdx.z == 1) ? B1 : B2;
  float* C = (blockIdx.z == 0) ? C0 : (blockIdx.z == 1) ? C1 : C2;
  __shared__ float As[16][128];   // transposed: As[k][m]
  __shared__ float Bs[16][128];   // Bs[k][n]
  const int m0 = blockIdx.y * 128;
  const int n0 = blockIdx.x * 128;
  const int t = threadIdx.x;
  const int tx = t & 15, ty = t >> 4;
  float acc[8][8];
#pragma unroll
  for (int i = 0; i < 8; ++i)
#pragma unroll
    for (int j = 0; j < 8; ++j) acc[i][j] = 0.f;

  for (int k0 = 0; k0 < K; k0 += 16) {
#pragma unroll
    for (int it = 0; it < 2; ++it) {
      int idx = t + it * 256;          // 0..511
      int row = idx >> 2;              // 0..127
      int kq = (idx & 3) * 4;          // 0,4,8,12
      float4 av = *(const float4*)(A + ((size_t)(m0 + row)) * K + k0 + kq);
      float4 bv = *(const float4*)(Bw + ((size_t)(n0 + row)) * K + k0 + kq);
      As[kq + 0][row] = av.x; As[kq + 1][row] = av.y;
      As[kq + 2][row] = av.z; As[kq + 3][row] = av.w;
      Bs[kq + 0][row] = bv.x; Bs[kq + 1][row] = bv.y;
      Bs[kq + 2][row] = bv.z; Bs[kq + 3][row] = bv.w;
    }
    __syncthreads();
#pragma unroll
    for (int kk = 0; kk < 16; ++kk) {
      float4 a0 = *(const float4*)&As[kk][ty * 4];
      float4 a1 = *(const float4*)&As[kk][64 + ty * 4];
      float4 b0 = *(const float4*)&Bs[kk][tx * 4];
      float4 b1 = *(const float4*)&Bs[kk][64 + tx * 4];
      float a[8] = {a0.x, a0.y, a0.z, a0.w, a1.x, a1.y, a1.z, a1.w};
      float bb[8] = {b0.x, b0.y, b0.z, b0.w, b1.x, b1.y, b1.z, b1.w};
#pragma unroll
      for (int i = 0; i < 8; ++i)
#pragma unroll
        for (int j = 0; j < 8; ++j)
          acc[i][j] = fmaf(a[i], bb[j], acc[i][j]);
    }
    __syncthreads();
  }
#pragma unroll
  for (int i = 0; i < 8; ++i) {
    int mi = m0 + ((i < 4) ? (ty * 4 + i) : (64 + ty * 4 + i - 4));
#pragma unroll
    for (int jb = 0; jb < 2; ++jb) {
      int nj = n0 + jb * 64 + tx * 4;
      float4 o;
      o.x = acc[i][jb * 4 + 0]; o.y = acc[i][jb * 4 + 1];
      o.z = acc[i][jb * 4 + 2]; o.w = acc[i][jb * 4 + 3];
      if (res) {
        float4 rv = *(const float4*)(res + (size_t)mi * N + nj);
        o.x += rv.x; o.y += rv.y; o.z += rv.z; o.w += rv.w;
      }
      *(float4*)(C + (size_t)mi * N + nj) = o;
    }
  }
}

// ---------------------------------------------------------------- RoPE (Q,K)
__global__ __launch_bounds__(256)
void rope_k(float* __restrict__ Q, float* __restrict__ K) {
  int idx = blockIdx.x * 256 + threadIdx.x;   // B*S*H*64 threads
  int d = idx & 63;
  int h = (idx >> 6) & (NHEAD - 1);
  int s = (idx >> 10) & (SEQL - 1);
  int b = idx >> 20;
  // inv_freq = 10000^(-d/64); compute in double for <=0.5ulp
  float invf = (float)exp(-(double)d * (9.210340371976184 / 64.0));
  float ang = (float)s * invf;
  float sn, c;
  sincosf(ang, &sn, &c);
  size_t base = ((size_t)(b * SEQL + s)) * DM + h * DHEAD + d;
  float q1 = Q[base], q2 = Q[base + 64];
  Q[base]      = q1 * c - q2 * sn;
  Q[base + 64] = q1 * sn + q2 * c;
  float k1 = K[base], k2 = K[base + 64];
  K[base]      = k1 * c - k2 * sn;
  K[base + 64] = k1 * sn + k2 * c;
}

// ------------------------------------- Fused causal flash attention + hadamard
// Grid: (S/64, B*H). 256 thr. Q,K tiles (64x128) in XOR-swizzled LDS; V via L2.
// score = (q.k + 0.1*sum((q*k)^2)) / sqrt(128); online softmax; P stored in K buf.
__global__ __launch_bounds__(256)
void flash_k(const float* __restrict__ Q, const float* __restrict__ K,
             const float* __restrict__ V, float* __restrict__ O) {
  __shared__ float Qs[64][128];
  __shared__ float Ks[64][128];
  float* Ps = &Ks[0][0];          // reused as P[64] stride 68 after scores
  const int qt = blockIdx.x;
  const int bh = blockIdx.y;
  const int b = bh >> 4, h = bh & 15;
  const int t = threadIdx.x;
  const int tx = t & 15, ty = t >> 4;
  const int i0 = ty * 4;          // 4 score rows
  const int j0 = tx * 4;          // 4 score cols
  const int c0 = tx * 8;          // 8 output cols

  const float* Qbase = Q + ((size_t)(b * SEQL + qt * 64)) * DM + h * DHEAD;
#pragma unroll
  for (int it = 0; it < 8; ++it) {
    int idx = t + it * 256;
    int row = idx >> 5;
    int c4 = idx & 31;
    float4 v = *(const float4*)(Qbase + (size_t)row * DM + c4 * 4);
    int c4s = c4 ^ ((row >> 2) & 7);   // bank-conflict swizzle
    *(float4*)&Qs[row][c4s * 4] = v;
  }

  float acc[4][8];
#pragma unroll
  for (int r = 0; r < 4; ++r)
#pragma unroll
    for (int e = 0; e < 8; ++e) acc[r][e] = 0.f;
  float mrun[4] = {-1e30f, -1e30f, -1e30f, -1e30f};
  float lrun[4] = {0.f, 0.f, 0.f, 0.f};

  for (int kt = 0; kt <= qt; ++kt) {
    __syncthreads();  // prev-iter P reads done (and first-iter Q staging done)
    const float* Kbase = K + ((size_t)(b * SEQL + kt * 64)) * DM + h * DHEAD;
#pragma unroll
    for (int it = 0; it < 8; ++it) {
      int idx = t + it * 256;
      int row = idx >> 5;
      int c4 = idx & 31;
      float4 v = *(const float4*)(Kbase + (size_t)row * DM + c4 * 4);
      int c4s = c4 ^ ((row >> 2) & 7);
      *(float4*)&Ks[row][c4s * 4] = v;
    }
    __syncthreads();

    float s1[4][4], s2[4][4];
#pragma unroll
    for (int r = 0; r < 4; ++r)
#pragma unroll
      for (int j = 0; j < 4; ++j) { s1[r][j] = 0.f; s2[r][j] = 0.f; }

#pragma unroll 4
    for (int d4 = 0; d4 < 32; ++d4) {
      float4 qv[4], kv[4];
#pragma unroll
      for (int r = 0; r < 4; ++r) {
        int i = i0 + r;
        qv[r] = *(const float4*)&Qs[i][(d4 ^ ((i >> 2) & 7)) * 4];
      }
#pragma unroll
      for (int j = 0; j < 4; ++j) {
        int jj = j0 + j;
        kv[j] = *(const float4*)&Ks[jj][(d4 ^ ((jj >> 2) & 7)) * 4];
      }
#pragma unroll
      for (int r = 0; r < 4; ++r)
#pragma unroll
        for (int j = 0; j < 4; ++j) {
          float t0 = qv[r].x * kv[j].x; s1[r][j] += t0; s2[r][j] = fmaf(t0, t0, s2[r][j]);
          float t1 = qv[r].y * kv[j].y; s1[r][j] += t1; s2[r][j] = fmaf(t1, t1, s2[r][j]);
          float t2 = qv[r].z * kv[j].z; s1[r][j] += t2; s2[r][j] = fmaf(t2, t2, s2[r][j]);
          float t3 = qv[r].w * kv[j].w; s1[r][j] += t3; s2[r][j] = fmaf(t3, t3, s2[r][j]);
        }
    }

    const float scale = 0.08838834764831845f;   // 1/sqrt(128)
    float p[4][4];
    const int igbase = qt * 64 + i0, jgbase = kt * 64 + j0;
#pragma unroll
    for (int r = 0; r < 4; ++r) {
      float sv[4];
#pragma unroll
      for (int j = 0; j < 4; ++j) {
        float x = (s1[r][j] + 0.1f * s2[r][j]) * scale;
        sv[j] = (jgbase + j > igbase + r) ? -1e30f : x;
      }
      float mx = fmaxf(fmaxf(sv[0], sv[1]), fmaxf(sv[2], sv[3]));
#pragma unroll
      for (int mm = 1; mm < 16; mm <<= 1) mx = fmaxf(mx, __shfl_xor(mx, mm, 64));
      float mnew = fmaxf(mrun[r], mx);
      float corr = __expf(mrun[r] - mnew);
      float rs = 0.f;
#pragma unroll
      for (int j = 0; j < 4; ++j) { p[r][j] = __expf(sv[j] - mnew); rs += p[r][j]; }
#pragma unroll
      for (int mm = 1; mm < 16; mm <<= 1) rs += __shfl_xor(rs, mm, 64);
      lrun[r] = lrun[r] * corr + rs;
      mrun[r] = mnew;
#pragma unroll
      for (int e = 0; e < 8; ++e) acc[r][e] *= corr;
    }
    __syncthreads();   // all K reads complete before P overwrites the buffer
#pragma unroll
    for (int r = 0; r < 4; ++r)
#pragma unroll
      for (int j = 0; j < 4; ++j)
        Ps[(i0 + r) * 68 + j0 + j] = p[r][j];
    __syncthreads();

    const float* Vbase = V + ((size_t)(b * SEQL + kt * 64)) * DM + h * DHEAD + c0;
#pragma unroll 4
    for (int j = 0; j < 64; ++j) {
      float4 v0 = *(const float4*)(Vbase + (size_t)j * DM);
      float4 v1 = *(const float4*)(Vbase + (size_t)j * DM + 4);
#pragma unroll
      for (int r = 0; r < 4; ++r) {
        float pr = Ps[(i0 + r) * 68 + j];
        acc[r][0] = fmaf(pr, v0.x, acc[r][0]);
        acc[r][1] = fmaf(pr, v0.y, acc[r][1]);
        acc[r][2] = fmaf(pr, v0.z, acc[r][2]);
        acc[r][3] = fmaf(pr, v0.w, acc[r][3]);
        acc[r][4] = fmaf(pr, v1.x, acc[r][4]);
        acc[r][5] = fmaf(pr, v1.y, acc[r][5]);
        acc[r][6] = fmaf(pr, v1.z, acc[r][6]);
        acc[r][7] = fmaf(pr, v1.w, acc[r][7]);
      }
    }
  }

  // Epilogue: normalize, hadamard mix over the 128-wide head (roll via shfl)
  float* Obase = O + ((size_t)(b * SEQL + qt * 64)) * DM + h * DHEAD;
  const int lane = t & 63;
  const int srcl = (lane & 48) | ((lane + 15) & 15);   // tx-1 (mod 16) same row grp
#pragma unroll
  for (int r = 0; r < 4; ++r) {
    float inv = 1.0f / lrun[r];
    float ov[8];
#pragma unroll
    for (int e = 0; e < 8; ++e) ov[e] = acc[r][e] * inv;
    float prev = __shfl(ov[7], srcl, 64);   // o[c0-1 mod 128]
    float4 o0, o1;
    o0.x = ov[0] + 0.05f * ov[0] * prev;
    o0.y = ov[1] + 0.05f * ov[1] * ov[0];
    o0.z = ov[2] + 0.05f * ov[2] * ov[1];
    o0.w = ov[3] + 0.05f * ov[3] * ov[2];
    o1.x = ov[4] + 0.05f * ov[4] * ov[3];
    o1.y = ov[5] + 0.05f * ov[5] * ov[4];
    o1.z = ov[6] + 0.05f * ov[6] * ov[5];
    o1.w = ov[7] + 0.05f * ov[7] * ov[6];
    *(float4*)(Obase + (size_t)(i0 + r) * DM + c0) = o0;
    *(float4*)(Obase + (size_t)(i0 + r) * DM + c0 + 4) = o1;
  }
}

// --------------------------------------- FFN: h = silu(g)*u, hadamard over F
__global__ __launch_bounds__(256)
void silu_mix_k(const float* __restrict__ G, const float* __restrict__ U,
                float* __restrict__ Ot) {
  __shared__ float hrow[FF];
  const int row = blockIdx.x;
  const size_t base = (size_t)row * FF;
  const float4* g4 = (const float4*)(G + base);
  const float4* u4 = (const float4*)(U + base);
#pragma unroll
  for (int it = 0; it < 8; ++it) {
    int c = threadIdx.x + it * 256;
    float4 g = g4[c], u = u4[c];
    float4 r;
    r.x = g.x / (1.f + __expf(-g.x)) * u.x;
    r.y = g.y / (1.f + __expf(-g.y)) * u.y;
    r.z = g.z / (1.f + __expf(-g.z)) * u.z;
    r.w = g.w / (1.f + __expf(-g.w)) * u.w;
    ((float4*)hrow)[c] = r;
  }
  __syncthreads();
  float4* o4 = (float4*)(Ot + base);
#pragma unroll
  for (int it = 0; it < 8; ++it) {
    int c = threadIdx.x + it * 256;
    float4 hv = ((float4*)hrow)[c];
    float hm = hrow[(c * 4 - 1) & (FF - 1)];
    float4 r;
    r.x = hv.x + 0.05f * hv.x * hm;
    r.y = hv.y + 0.05f * hv.y * hv.x;
    r.z = hv.z + 0.05f * hv.z * hv.y;
    r.w = hv.w + 0.05f * hv.w * hv.z;
    o4[c] = r;
  }
}

// ---------------------------------------------------------------- elementwise
__global__ __launch_bounds__(256)
void axpb_k(const float* __restrict__ a, const float* __restrict__ b,
            float* __restrict__ o) {   // o = a + 0.3*(a-b)
  size_t i = (size_t)blockIdx.x * 256 + threadIdx.x;
  float4 av = ((const float4*)a)[i];
  float4 bv = ((const float4*)b)[i];
  float4 r;
  r.x = av.x + 0.3f * (av.x - bv.x);
  r.y = av.y + 0.3f * (av.y - bv.y);
  r.z = av.z + 0.3f * (av.z - bv.z);
  r.w = av.w + 0.3f * (av.w - bv.w);
  ((float4*)o)[i] = r;
}

__global__ __launch_bounds__(256)
void final_k(const float* __restrict__ a, const float* __restrict__ b,
             float* __restrict__ o) {  // o = clip(0.5*(a+b), -10, 10)
  size_t i = (size_t)blockIdx.x * 256 + threadIdx.x;
  float4 av = ((const float4*)a)[i];
  float4 bv = ((const float4*)b)[i];
  float4 r;
  r.x = fminf(10.f, fmaxf(-10.f, 0.5f * av.x + 0.5f * bv.x));
  r.y = fminf(10.f, fmaxf(-10.f, 0.5f * av.y + 0.5f * bv.y));
  r.z = fminf(10.f, fmaxf(-10.f, 0.5f * av.z + 0.5f * bv.z));
  r.w = fminf(10.f, fmaxf(-10.f, 0.5f * av.w + 0.5f * bv.w));
  ((float4*)o)[i] = r;
}

// ---------------------------------------------------------------- driver
static void run_gemm(const float* A, const float* B0, const float* B1,
                     const float* B2, float* C0, float* C1, float* C2,
                     const float* res, int M, int N, int K, int Z,
                     hipStream_t st) {
  dim3 g(N / 128, M / 128, Z);
  gemm_nt<<<g, 256, 0, st>>>(A, B0, B1, B2, C0, C1, C2, res, M, N, K);
}

extern "C" void kernel_launch(void* const* d_in, const int* in_sizes, int n_in,
                              void* d_out, int out_size, void* d_ws, size_t ws_size,
                              hipStream_t stream) {
  const float* x  = (const float*)d_in[0];
  const float* Wq = (const float*)d_in[1];
  const float* Wk = (const float*)d_in[2];
  const float* Wv = (const float*)d_in[3];
  const float* Wo = (const float*)d_in[4];
  // d_in[5] = gate_w: unused (o1==o2 identity)
  const float* n1 = (const float*)d_in[6];
  const float* n2 = (const float*)d_in[7];
  const float* n3 = (const float*)d_in[8];
  const float* n4 = (const float*)d_in[9];
  const float* Wg = (const float*)d_in[10];
  const float* Wu = (const float*)d_in[11];
  const float* Wd = (const float*)d_in[12];
  float* out = (float*)d_out;

  float* w = (float*)d_ws;
  const size_t TD = (size_t)TOK * DM;       // 4M floats
  float* XN   = w;            // rmsnorm out; reused as attention output
  float* Qb   = w + 1 * TD;
  float* Kb   = w + 2 * TD;
  float* Vb   = w + 3 * TD;
  float* XMID = w + 4 * TD;
  float* H1   = w + 5 * TD;
  float* X2   = w + 6 * TD;
  float* H2   = w + 7 * TD;
  float* G    = w + 8 * TD;   // TOK x FF
  float* U    = w + 12 * TD;  // TOK x FF
  // total ws use: 16*TD floats = 256 MiB

  auto pass = [&](const float* xin, float* xout, const float* na, const float* nb) {
    rmsnorm_k<<<TOK, 256, 0, stream>>>(xin, na, XN);
    run_gemm(XN, Wq, Wk, Wv, Qb, Kb, Vb, nullptr, TOK, DM, DM, 3, stream);
    rope_k<<<(NBATCH * SEQL * NHEAD * 64) / 256, 256, 0, stream>>>(Qb, Kb);
    flash_k<<<dim3(SEQL / 64, NBATCH * NHEAD), 256, 0, stream>>>(Qb, Kb, Vb, XN);
    run_gemm(XN, Wo, nullptr, nullptr, XMID, nullptr, nullptr, xin,
             TOK, DM, DM, 1, stream);
    rmsnorm_k<<<TOK, 256, 0, stream>>>(XMID, nb, XN);
    run_gemm(XN, Wg, Wu, nullptr, G, U, nullptr, nullptr, TOK, FF, DM, 2, stream);
    silu_mix_k<<<TOK, 256, 0, stream>>>(G, U, G);   // safe: per-row, barrier-split
    run_gemm(G, Wd, nullptr, nullptr, xout, nullptr, nullptr, XMID,
             TOK, DM, FF, 1, stream);
  };

  pass(x, H1, n1, n2);
  axpb_k<<<TD / 1024, 256, 0, stream>>>(H1, x, X2);   // X2 = 1.3*H1 - 0.3*x
  pass(X2, H2, n3, n4);
  final_k<<<TD / 1024, 256, 0, stream>>>(H1, H2, out);
}

// Round 4
// 3346.560 us; speedup vs baseline: 2.3879x; 2.3879x over previous
//
#include <hip/hip_runtime.h>
#include <math.h>

// Shapes (fixed): B=2, S=1024, D=2048, H=16, DH=128, F=8192
#define SEQL 1024
#define NBATCH 2
#define NHEAD 16
#define DHEAD 128
#define DM 2048
#define FF 8192
#define TOK 2048   // B*S

// KEY IDENTITY: attn_pass(rotate_half(Q), rotate_half(K), V) == attn_pass(Q,K,V)
// -> o1 == o2 -> gate vanishes; one attention pass.
//
// R3 = R2 (bf16x3 MFMA GEMMs) restructured into a PROVEN 256 MiB workspace:
//  - weight splits recomputed per phase into a rotating 64 MiB region
//  - Q/K/V alias G/U (disjoint phases); AO aliases XN; d_out doubles as H2.

typedef short bf16x8 __attribute__((ext_vector_type(8)));   // 8 bf16 in 4 VGPRs
typedef float f32x4 __attribute__((ext_vector_type(4)));

__device__ __forceinline__ ushort f2bf(float f) {
  unsigned u = __float_as_uint(f);
  u += 0x7fffu + ((u >> 16) & 1u);    // RNE
  return (ushort)(u >> 16);
}
__device__ __forceinline__ float bf2f(ushort s) {
  return __uint_as_float(((unsigned)s) << 16);
}
__device__ __forceinline__ void splitf(float a, ushort& h, ushort& l) {
  h = f2bf(a);
  l = f2bf(a - bf2f(h));
}

__device__ __forceinline__ void g2l16(const ushort* g, ushort* l) {
  __builtin_amdgcn_global_load_lds(
      (const __attribute__((address_space(1))) void*)g,
      (__attribute__((address_space(3))) void*)l, 16, 0, 0);
}

// ---------------------------------------------------------------- weight split
__global__ __launch_bounds__(256)
void split_k(const float* __restrict__ a, ushort* __restrict__ h,
             ushort* __restrict__ l) {
  size_t i = (size_t)blockIdx.x * 256 + threadIdx.x;
  float4 v = ((const float4*)a)[i];
  ushort4 hh, ll;
  splitf(v.x, hh.x, ll.x);
  splitf(v.y, hh.y, ll.y);
  splitf(v.z, hh.z, ll.z);
  splitf(v.w, hh.w, ll.w);
  ((ushort4*)h)[i] = hh;
  ((ushort4*)l)[i] = ll;
}

// ---------------------------------------------------- RMSNorm -> hi/lo bf16
__global__ __launch_bounds__(256)
void rmsnorm_split_k(const float* __restrict__ x, const float* __restrict__ g,
                     ushort* __restrict__ oh, ushort* __restrict__ ol) {
  const int row = blockIdx.x;
  const int t = threadIdx.x;
  const float4* xr = (const float4*)(x + (size_t)row * DM);
  float4 v0 = xr[t], v1 = xr[t + 256];
  float ss = v0.x*v0.x + v0.y*v0.y + v0.z*v0.z + v0.w*v0.w
           + v1.x*v1.x + v1.y*v1.y + v1.z*v1.z + v1.w*v1.w;
#pragma unroll
  for (int m = 1; m < 64; m <<= 1) ss += __shfl_xor(ss, m, 64);
  __shared__ float wsum[4];
  if ((t & 63) == 0) wsum[t >> 6] = ss;
  __syncthreads();
  float tot = wsum[0] + wsum[1] + wsum[2] + wsum[3];
  float sc = rsqrtf(tot * (1.0f / DM) + 1e-6f);
  const float4* gr = (const float4*)g;
  float4 g0 = gr[t], g1 = gr[t + 256];
  float o[8] = {v0.x*sc*g0.x, v0.y*sc*g0.y, v0.z*sc*g0.z, v0.w*sc*g0.w,
                v1.x*sc*g1.x, v1.y*sc*g1.y, v1.z*sc*g1.z, v1.w*sc*g1.w};
  ushort4 h0, h1, l0, l1;
  splitf(o[0], h0.x, l0.x); splitf(o[1], h0.y, l0.y);
  splitf(o[2], h0.z, l0.z); splitf(o[3], h0.w, l0.w);
  splitf(o[4], h1.x, l1.x); splitf(o[5], h1.y, l1.y);
  splitf(o[6], h1.z, l1.z); splitf(o[7], h1.w, l1.w);
  ushort4* ohr = (ushort4*)(oh + (size_t)row * DM);
  ushort4* olr = (ushort4*)(ol + (size_t)row * DM);
  ohr[t] = h0; ohr[t + 256] = h1;
  olr[t] = l0; olr[t + 256] = l1;
}

// -------------------------------------------- MFMA GEMM: C = A*B^T (+res)
// A: MxK (hi/lo bf16, row stride lda), B: NxK (hi/lo bf16, dense), C fp32.
// 128x128 tile, BK=32, 4 waves (2x2, 64x64 each), 16x16x32 MFMA, 3 chains
// (hh, hl, lh). 2-phase LDS double-buffer: stage(k+1) issued before
// compute(k); the __syncthreads vmcnt drain lands after the MFMA phase.
__global__ __launch_bounds__(256, 2)
void gemm_bf16x3(const ushort* __restrict__ Ah, const ushort* __restrict__ Al,
                 const ushort* __restrict__ Bh0, const ushort* __restrict__ Bl0,
                 const ushort* __restrict__ Bh1, const ushort* __restrict__ Bl1,
                 const ushort* __restrict__ Bh2, const ushort* __restrict__ Bl2,
                 float* __restrict__ C0, float* __restrict__ C1,
                 float* __restrict__ C2, const float* __restrict__ res,
                 int M, int N, int K, int lda) {
  const ushort* Bh = (blockIdx.z == 0) ? Bh0 : (blockIdx.z == 1) ? Bh1 : Bh2;
  const ushort* Bl = (blockIdx.z == 0) ? Bl0 : (blockIdx.z == 1) ? Bl1 : Bl2;
  float* C = (blockIdx.z == 0) ? C0 : (blockIdx.z == 1) ? C1 : C2;
  __shared__ ushort lds[2][4][128 * 32];   // [buf][Ah|Al|Bh|Bl][row*32+k]
  const int t = threadIdx.x;
  const int m0 = blockIdx.y * 128, n0 = blockIdx.x * 128;
  const int lane = t & 63, w = t >> 6;
  const int wr = (w >> 1) * 64, wc = (w & 1) * 64;
  const int fr = lane & 15, fq = lane >> 4;

  f32x4 acc[4][4];
#pragma unroll
  for (int m = 0; m < 4; ++m)
#pragma unroll
    for (int n = 0; n < 4; ++n) acc[m][n] = f32x4{0.f, 0.f, 0.f, 0.f};

  auto stage = [&](int k0, int buf) {
#pragma unroll
    for (int it = 0; it < 2; ++it) {
      int c = it * 256 + t;               // chunk 0..511; 16B each
      int row = c >> 2, kc = (c & 3) * 8;
      size_t ao = (size_t)(m0 + row) * lda + k0 + kc;
      size_t bo = (size_t)(n0 + row) * K + k0 + kc;
      g2l16(Ah + ao, &lds[buf][0][c * 8]);
      g2l16(Al + ao, &lds[buf][1][c * 8]);
      g2l16(Bh + bo, &lds[buf][2][c * 8]);
      g2l16(Bl + bo, &lds[buf][3][c * 8]);
    }
  };

  const int nt = K >> 5;
  stage(0, 0);
  __syncthreads();
  const int aoff = (wr + fr) * 4 + fq;    // bf16x8-chunk index, +64 per m-frag
  const int boff = (wc + fr) * 4 + fq;
  for (int tk = 0; tk < nt; ++tk) {
    int cur = tk & 1;
    if (tk + 1 < nt) stage((tk + 1) << 5, cur ^ 1);
    const bf16x8* pa_h = (const bf16x8*)&lds[cur][0][0];
    const bf16x8* pa_l = (const bf16x8*)&lds[cur][1][0];
    const bf16x8* pb_h = (const bf16x8*)&lds[cur][2][0];
    const bf16x8* pb_l = (const bf16x8*)&lds[cur][3][0];
    bf16x8 ah[4], al[4], bh[4], bl[4];
#pragma unroll
    for (int m = 0; m < 4; ++m) {
      ah[m] = pa_h[aoff + m * 64];
      al[m] = pa_l[aoff + m * 64];
    }
#pragma unroll
    for (int n = 0; n < 4; ++n) {
      bh[n] = pb_h[boff + n * 64];
      bl[n] = pb_l[boff + n * 64];
    }
#pragma unroll
    for (int m = 0; m < 4; ++m)
#pragma unroll
      for (int n = 0; n < 4; ++n) {
        acc[m][n] = __builtin_amdgcn_mfma_f32_16x16x32_bf16(ah[m], bh[n], acc[m][n], 0, 0, 0);
        acc[m][n] = __builtin_amdgcn_mfma_f32_16x16x32_bf16(ah[m], bl[n], acc[m][n], 0, 0, 0);
        acc[m][n] = __builtin_amdgcn_mfma_f32_16x16x32_bf16(al[m], bh[n], acc[m][n], 0, 0, 0);
      }
    __syncthreads();   // drains stage(tk+1) loads + guards LDS reuse
  }

  // Epilogue: C/D layout col=lane&15, row=(lane>>4)*4+i  [m89/m91 verified]
#pragma unroll
  for (int m = 0; m < 4; ++m) {
    int gr = m0 + wr + m * 16 + fq * 4;
#pragma unroll
    for (int n = 0; n < 4; ++n) {
      int gc = n0 + wc + n * 16 + fr;
      f32x4 v = acc[m][n];
#pragma unroll
      for (int i = 0; i < 4; ++i) {
        size_t off = (size_t)(gr + i) * N + gc;
        float o = v[i];
        if (res) o += res[off];
        C[off] = o;
      }
    }
  }
}

// ---------------------------------------------------------------- RoPE (Q,K)
__global__ __launch_bounds__(256)
void rope_k(float* __restrict__ Q, float* __restrict__ K) {
  int idx = blockIdx.x * 256 + threadIdx.x;   // B*S*H*64 threads
  int d = idx & 63;
  int h = (idx >> 6) & (NHEAD - 1);
  int s = (idx >> 10) & (SEQL - 1);
  int b = idx >> 20;
  float invf = (float)exp(-(double)d * (9.210340371976184 / 64.0));
  float ang = (float)s * invf;
  float sn, c;
  sincosf(ang, &sn, &c);
  size_t base = ((size_t)(b * SEQL + s)) * DM + h * DHEAD + d;
  float q1 = Q[base], q2 = Q[base + 64];
  Q[base]      = q1 * c - q2 * sn;
  Q[base + 64] = q1 * sn + q2 * c;
  float k1 = K[base], k2 = K[base + 64];
  K[base]      = k1 * c - k2 * sn;
  K[base + 64] = k1 * sn + k2 * c;
}

// ------------------------------------- Fused causal flash attention + hadamard
// Epilogue emits hi/lo bf16 for the Wo GEMM.
__global__ __launch_bounds__(256)
void flash_k(const float* __restrict__ Q, const float* __restrict__ K,
             const float* __restrict__ V, ushort* __restrict__ OH,
             ushort* __restrict__ OL) {
  __shared__ float Qs[64][128];
  __shared__ float Ks[64][128];
  float* Ps = &Ks[0][0];          // reused as P[64] stride 68 after scores
  const int qt = blockIdx.x;
  const int bh = blockIdx.y;
  const int b = bh >> 4, h = bh & 15;
  const int t = threadIdx.x;
  const int tx = t & 15, ty = t >> 4;
  const int i0 = ty * 4;
  const int j0 = tx * 4;
  const int c0 = tx * 8;

  const float* Qbase = Q + ((size_t)(b * SEQL + qt * 64)) * DM + h * DHEAD;
#pragma unroll
  for (int it = 0; it < 8; ++it) {
    int idx = t + it * 256;
    int row = idx >> 5;
    int c4 = idx & 31;
    float4 v = *(const float4*)(Qbase + (size_t)row * DM + c4 * 4);
    int c4s = c4 ^ ((row >> 2) & 7);
    *(float4*)&Qs[row][c4s * 4] = v;
  }

  float acc[4][8];
#pragma unroll
  for (int r = 0; r < 4; ++r)
#pragma unroll
    for (int e = 0; e < 8; ++e) acc[r][e] = 0.f;
  float mrun[4] = {-1e30f, -1e30f, -1e30f, -1e30f};
  float lrun[4] = {0.f, 0.f, 0.f, 0.f};

  for (int kt = 0; kt <= qt; ++kt) {
    __syncthreads();
    const float* Kbase = K + ((size_t)(b * SEQL + kt * 64)) * DM + h * DHEAD;
#pragma unroll
    for (int it = 0; it < 8; ++it) {
      int idx = t + it * 256;
      int row = idx >> 5;
      int c4 = idx & 31;
      float4 v = *(const float4*)(Kbase + (size_t)row * DM + c4 * 4);
      int c4s = c4 ^ ((row >> 2) & 7);
      *(float4*)&Ks[row][c4s * 4] = v;
    }
    __syncthreads();

    float s1[4][4], s2[4][4];
#pragma unroll
    for (int r = 0; r < 4; ++r)
#pragma unroll
      for (int j = 0; j < 4; ++j) { s1[r][j] = 0.f; s2[r][j] = 0.f; }

#pragma unroll 4
    for (int d4 = 0; d4 < 32; ++d4) {
      float4 qv[4], kv[4];
#pragma unroll
      for (int r = 0; r < 4; ++r) {
        int i = i0 + r;
        qv[r] = *(const float4*)&Qs[i][(d4 ^ ((i >> 2) & 7)) * 4];
      }
#pragma unroll
      for (int j = 0; j < 4; ++j) {
        int jj = j0 + j;
        kv[j] = *(const float4*)&Ks[jj][(d4 ^ ((jj >> 2) & 7)) * 4];
      }
#pragma unroll
      for (int r = 0; r < 4; ++r)
#pragma unroll
        for (int j = 0; j < 4; ++j) {
          float t0 = qv[r].x * kv[j].x; s1[r][j] += t0; s2[r][j] = fmaf(t0, t0, s2[r][j]);
          float t1 = qv[r].y * kv[j].y; s1[r][j] += t1; s2[r][j] = fmaf(t1, t1, s2[r][j]);
          float t2 = qv[r].z * kv[j].z; s1[r][j] += t2; s2[r][j] = fmaf(t2, t2, s2[r][j]);
          float t3 = qv[r].w * kv[j].w; s1[r][j] += t3; s2[r][j] = fmaf(t3, t3, s2[r][j]);
        }
    }

    const float scale = 0.08838834764831845f;   // 1/sqrt(128)
    float p[4][4];
    const int igbase = qt * 64 + i0, jgbase = kt * 64 + j0;
#pragma unroll
    for (int r = 0; r < 4; ++r) {
      float sv[4];
#pragma unroll
      for (int j = 0; j < 4; ++j) {
        float x = (s1[r][j] + 0.1f * s2[r][j]) * scale;
        sv[j] = (jgbase + j > igbase + r) ? -1e30f : x;
      }
      float mx = fmaxf(fmaxf(sv[0], sv[1]), fmaxf(sv[2], sv[3]));
#pragma unroll
      for (int mm = 1; mm < 16; mm <<= 1) mx = fmaxf(mx, __shfl_xor(mx, mm, 64));
      float mnew = fmaxf(mrun[r], mx);
      float corr = __expf(mrun[r] - mnew);
      float rs = 0.f;
#pragma unroll
      for (int j = 0; j < 4; ++j) { p[r][j] = __expf(sv[j] - mnew); rs += p[r][j]; }
#pragma unroll
      for (int mm = 1; mm < 16; mm <<= 1) rs += __shfl_xor(rs, mm, 64);
      lrun[r] = lrun[r] * corr + rs;
      mrun[r] = mnew;
#pragma unroll
      for (int e = 0; e < 8; ++e) acc[r][e] *= corr;
    }
    __syncthreads();
#pragma unroll
    for (int r = 0; r < 4; ++r)
#pragma unroll
      for (int j = 0; j < 4; ++j)
        Ps[(i0 + r) * 68 + j0 + j] = p[r][j];
    __syncthreads();

    const float* Vbase = V + ((size_t)(b * SEQL + kt * 64)) * DM + h * DHEAD + c0;
#pragma unroll 4
    for (int j = 0; j < 64; ++j) {
      float4 v0 = *(const float4*)(Vbase + (size_t)j * DM);
      float4 v1 = *(const float4*)(Vbase + (size_t)j * DM + 4);
#pragma unroll
      for (int r = 0; r < 4; ++r) {
        float pr = Ps[(i0 + r) * 68 + j];
        acc[r][0] = fmaf(pr, v0.x, acc[r][0]);
        acc[r][1] = fmaf(pr, v0.y, acc[r][1]);
        acc[r][2] = fmaf(pr, v0.z, acc[r][2]);
        acc[r][3] = fmaf(pr, v0.w, acc[r][3]);
        acc[r][4] = fmaf(pr, v1.x, acc[r][4]);
        acc[r][5] = fmaf(pr, v1.y, acc[r][5]);
        acc[r][6] = fmaf(pr, v1.z, acc[r][6]);
        acc[r][7] = fmaf(pr, v1.w, acc[r][7]);
      }
    }
  }

  ushort* OHb = OH + ((size_t)(b * SEQL + qt * 64)) * DM + h * DHEAD;
  ushort* OLb = OL + ((size_t)(b * SEQL + qt * 64)) * DM + h * DHEAD;
  const int lane = t & 63;
  const int srcl = (lane & 48) | ((lane + 15) & 15);
#pragma unroll
  for (int r = 0; r < 4; ++r) {
    float inv = 1.0f / lrun[r];
    float ov[8];
#pragma unroll
    for (int e = 0; e < 8; ++e) ov[e] = acc[r][e] * inv;
    float prev = __shfl(ov[7], srcl, 64);
    float mx[8];
    mx[0] = ov[0] + 0.05f * ov[0] * prev;
#pragma unroll
    for (int e = 1; e < 8; ++e) mx[e] = ov[e] + 0.05f * ov[e] * ov[e - 1];
    ushort4 hh0, hh1, ll0, ll1;
    splitf(mx[0], hh0.x, ll0.x); splitf(mx[1], hh0.y, ll0.y);
    splitf(mx[2], hh0.z, ll0.z); splitf(mx[3], hh0.w, ll0.w);
    splitf(mx[4], hh1.x, ll1.x); splitf(mx[5], hh1.y, ll1.y);
    splitf(mx[6], hh1.z, ll1.z); splitf(mx[7], hh1.w, ll1.w);
    size_t ro = (size_t)(i0 + r) * DM + c0;
    *(ushort4*)(OHb + ro) = hh0; *(ushort4*)(OHb + ro + 4) = hh1;
    *(ushort4*)(OLb + ro) = ll0; *(ushort4*)(OLb + ro + 4) = ll1;
  }
}

// --------------------------- FFN: h = silu(g)*u, hadamard, -> hi/lo bf16
// In-place alias of G/U is safe: bf16 row r occupies the FIRST HALF of fp32
// row r's own byte range (row stride 2*FF ushorts), so no other block's read
// region is touched; within the block all reads precede the barrier.
__global__ __launch_bounds__(256)
void silu_mix_k(const float* G, const float* U, ushort* oh, ushort* ol) {
  __shared__ float hrow[FF];
  const int row = blockIdx.x;
  const size_t base = (size_t)row * FF;        // fp32 row
  const size_t base2 = (size_t)row * (2 * FF); // bf16 row (same byte offset)
  const float4* g4 = (const float4*)(G + base);
  const float4* u4 = (const float4*)(U + base);
#pragma unroll
  for (int it = 0; it < 8; ++it) {
    int c = threadIdx.x + it * 256;
    float4 g = g4[c], u = u4[c];
    float4 r;
    r.x = g.x / (1.f + __expf(-g.x)) * u.x;
    r.y = g.y / (1.f + __expf(-g.y)) * u.y;
    r.z = g.z / (1.f + __expf(-g.z)) * u.z;
    r.w = g.w / (1.f + __expf(-g.w)) * u.w;
    ((float4*)hrow)[c] = r;
  }
  __syncthreads();
#pragma unroll
  for (int it = 0; it < 8; ++it) {
    int c = threadIdx.x + it * 256;
    float4 hv = ((float4*)hrow)[c];
    float hm = hrow[(c * 4 - 1) & (FF - 1)];
    float m0 = hv.x + 0.05f * hv.x * hm;
    float m1 = hv.y + 0.05f * hv.y * hv.x;
    float m2 = hv.z + 0.05f * hv.z * hv.y;
    float m3 = hv.w + 0.05f * hv.w * hv.z;
    ushort4 h4, l4;
    splitf(m0, h4.x, l4.x); splitf(m1, h4.y, l4.y);
    splitf(m2, h4.z, l4.z); splitf(m3, h4.w, l4.w);
    ((ushort4*)(oh + base2))[c] = h4;
    ((ushort4*)(ol + base2))[c] = l4;
  }
}

// ---------------------------------------------------------------- elementwise
__global__ __launch_bounds__(256)
void axpb_k(const float* __restrict__ a, const float* __restrict__ b,
            float* __restrict__ o) {   // o = a + 0.3*(a-b)
  size_t i = (size_t)blockIdx.x * 256 + threadIdx.x;
  float4 av = ((const float4*)a)[i];
  float4 bv = ((const float4*)b)[i];
  float4 r;
  r.x = av.x + 0.3f * (av.x - bv.x);
  r.y = av.y + 0.3f * (av.y - bv.y);
  r.z = av.z + 0.3f * (av.z - bv.z);
  r.w = av.w + 0.3f * (av.w - bv.w);
  ((float4*)o)[i] = r;
}

__global__ __launch_bounds__(256)
void final_k(const float* __restrict__ a, float* __restrict__ o) {
  // o = clip(0.5*a + 0.5*o, -10, 10); o read-then-write same index (no race)
  size_t i = (size_t)blockIdx.x * 256 + threadIdx.x;
  float4 av = ((const float4*)a)[i];
  float4 bv = ((float4*)o)[i];
  float4 r;
  r.x = fminf(10.f, fmaxf(-10.f, 0.5f * av.x + 0.5f * bv.x));
  r.y = fminf(10.f, fmaxf(-10.f, 0.5f * av.y + 0.5f * bv.y));
  r.z = fminf(10.f, fmaxf(-10.f, 0.5f * av.z + 0.5f * bv.z));
  r.w = fminf(10.f, fmaxf(-10.f, 0.5f * av.w + 0.5f * bv.w));
  ((float4*)o)[i] = r;
}

// ---------------------------------------------------------------- driver
extern "C" void kernel_launch(void* const* d_in, const int* in_sizes, int n_in,
                              void* d_out, int out_size, void* d_ws, size_t ws_size,
                              hipStream_t stream) {
  const float* x  = (const float*)d_in[0];
  const float* Wq = (const float*)d_in[1];
  const float* Wk = (const float*)d_in[2];
  const float* Wv = (const float*)d_in[3];
  const float* Wo = (const float*)d_in[4];
  const float* n1 = (const float*)d_in[6];
  const float* n2 = (const float*)d_in[7];
  const float* n3 = (const float*)d_in[8];
  const float* n4 = (const float*)d_in[9];
  const float* Wg = (const float*)d_in[10];
  const float* Wu = (const float*)d_in[11];
  const float* Wd = (const float*)d_in[12];
  float* out = (float*)d_out;

  // ---- workspace map: 256 MiB total (proven available by R0's passing run)
  char* wb = (char*)d_ws;
  const size_t MB = 1024ull * 1024ull;
  // [0,128): attention phase Q/K/V  |  FFN phase G/U (+in-place HID bf16)
  float*  Qb  = (float*)(wb + 0 * MB);     // 16 MB
  float*  Kb  = (float*)(wb + 16 * MB);    // 16 MB
  float*  Vb  = (float*)(wb + 32 * MB);    // 16 MB
  float*  G   = (float*)(wb + 0 * MB);     // 64 MB (aliases Q/K/V: disjoint phase)
  float*  U   = (float*)(wb + 64 * MB);    // 64 MB
  ushort* HIDh = (ushort*)G;               // bf16 rows, stride 2*FF ushorts
  ushort* HIDl = (ushort*)U;
  float*  XMID = (float*)(wb + 128 * MB);  // 16 MB
  float*  H1   = (float*)(wb + 144 * MB);  // 16 MB
  float*  X2   = (float*)(wb + 160 * MB);  // 16 MB
  ushort* XNh  = (ushort*)(wb + 176 * MB); // 8 MB
  ushort* XNl  = (ushort*)(wb + 184 * MB); // 8 MB
  ushort* AOh  = XNh;                      // alias: XN dead after QKV gemm,
  ushort* AOl  = XNl;                      //        rewritten only after Wo gemm
  char*   WS   = wb + 192 * MB;            // 64 MB rotating weight-split region
  float*  H2   = out;                      // d_out doubles as pass-2 output

  const int DD4 = DM * DM / 1024;          // split_k blocks for DxD
  const int FD4 = FF * DM / 1024;          //                  for FxD

  auto gemm = [&](const ushort* Ah, const ushort* Al,
                  const ushort* Bh0, const ushort* Bl0,
                  const ushort* Bh1, const ushort* Bl1,
                  const ushort* Bh2, const ushort* Bl2,
                  float* C0, float* C1, float* C2, const float* res,
                  int M, int N, int K, int lda, int Z) {
    dim3 g(N / 128, M / 128, Z);
    gemm_bf16x3<<<g, 256, 0, stream>>>(Ah, Al, Bh0, Bl0, Bh1, Bl1, Bh2, Bl2,
                                       C0, C1, C2, res, M, N, K, lda);
  };

  // Rotating split slots (all inside WS; stream order serializes reuse)
  ushort* sA_h = (ushort*)(WS + 0 * MB);   // DxD hi (8 MB) / FxD hi (32 MB)
  ushort* sA_l = (ushort*)(WS + 8 * MB);   // DxD lo
  ushort* sB_h = (ushort*)(WS + 16 * MB);
  ushort* sB_l = (ushort*)(WS + 24 * MB);
  ushort* sC_h = (ushort*)(WS + 32 * MB);  // FxD lo lives here (32 MB)
  ushort* sC_l = (ushort*)(WS + 40 * MB);
  ushort* sF_h = sA_h;                     // FxD hi slot
  ushort* sF_l = sC_h;                     // FxD lo slot

  auto pass = [&](const float* xin, float* xout, const float* na, const float* nb) {
    // ---- attention
    split_k<<<DD4, 256, 0, stream>>>(Wq, sA_h, sA_l);
    split_k<<<DD4, 256, 0, stream>>>(Wk, sB_h, sB_l);
    split_k<<<DD4, 256, 0, stream>>>(Wv, sC_h, sC_l);
    rmsnorm_split_k<<<TOK, 256, 0, stream>>>(xin, na, XNh, XNl);
    gemm(XNh, XNl, sA_h, sA_l, sB_h, sB_l, sC_h, sC_l, Qb, Kb, Vb, nullptr,
         TOK, DM, DM, DM, 3);
    rope_k<<<(NBATCH * SEQL * NHEAD * 64) / 256, 256, 0, stream>>>(Qb, Kb);
    flash_k<<<dim3(SEQL / 64, NBATCH * NHEAD), 256, 0, stream>>>(Qb, Kb, Vb, AOh, AOl);
    split_k<<<DD4, 256, 0, stream>>>(Wo, sA_h, sA_l);
    gemm(AOh, AOl, sA_h, sA_l, nullptr, nullptr, nullptr, nullptr,
         XMID, nullptr, nullptr, xin, TOK, DM, DM, DM, 1);
    // ---- FFN
    rmsnorm_split_k<<<TOK, 256, 0, stream>>>(XMID, nb, XNh, XNl);
    split_k<<<FD4, 256, 0, stream>>>(Wg, sF_h, sF_l);
    gemm(XNh, XNl, sF_h, sF_l, nullptr, nullptr, nullptr, nullptr,
         G, nullptr, nullptr, nullptr, TOK, FF, DM, DM, 1);
    split_k<<<FD4, 256, 0, stream>>>(Wu, sF_h, sF_l);
    gemm(XNh, XNl, sF_h, sF_l, nullptr, nullptr, nullptr, nullptr,
         U, nullptr, nullptr, nullptr, TOK, FF, DM, DM, 1);
    silu_mix_k<<<TOK, 256, 0, stream>>>(G, U, HIDh, HIDl);
    split_k<<<FD4, 256, 0, stream>>>(Wd, sF_h, sF_l);
    gemm(HIDh, HIDl, sF_h, sF_l, nullptr, nullptr, nullptr, nullptr,
         xout, nullptr, nullptr, XMID, TOK, DM, FF, 2 * FF, 1);
  };

  const size_t TD = (size_t)TOK * DM;
  pass(x, H1, n1, n2);
  axpb_k<<<TD / 1024, 256, 0, stream>>>(H1, x, X2);   // X2 = 1.3*H1 - 0.3*x
  pass(X2, H2, n3, n4);
  final_k<<<TD / 1024, 256, 0, stream>>>(H1, out);    // out = clip(.5*H1+.5*H2)
}